// Round 5
// baseline (464.390 us; speedup 1.0000x reference)
//
#include <hip/hip_runtime.h>
#include <math.h>
#include <stdint.h>

// B=8,S=2048,D=512,I=1024,E=8,K=2,SH=2048 ; T=16384 tokens
#define T_TOK 16384
#define DDIM  512
#define IDIM  1024
#define NEXP  8
#define SHDIM 2048
#define MPAD  34816                // routed rows padded: 2T + 8*255 -> ceil to 136*256
#define GBLK  256                  // k_gate blocks (64 tokens each)

typedef unsigned short u16;
typedef short bf16x8 __attribute__((ext_vector_type(8)));
typedef float f32x4 __attribute__((ext_vector_type(4)));

__device__ __forceinline__ u16 f2bf(float f) {
    unsigned u = __float_as_uint(f);
    u += 0x7FFF + ((u >> 16) & 1);   // round-to-nearest-even
    return (u16)(u >> 16);
}
__device__ __forceinline__ float bf2f(u16 h) {
    return __uint_as_float((unsigned)h << 16);
}

__device__ __forceinline__ void gload_lds16(const void* g, void* l) {
    __builtin_amdgcn_global_load_lds(
        (const __attribute__((address_space(1))) void*)g,
        (__attribute__((address_space(3))) void*)l, 16, 0, 0);
}

// XCD-chunked bijective block swizzle (T1); nwg % 8 == 0 for all our grids.
__device__ __forceinline__ int xcd_swz(int id, int nwg) {
    return (id & 7) * (nwg >> 3) + (id >> 3);
}

// ---------------- routing ----------------
__global__ void k_zero(int* cursors) {
    int i = threadIdx.x;
    if (i < NEXP) cursors[i] = 0;
}

// 64 tokens/block, 4 waves. No global atomics; fuses x->bf16 (writes xb).
__global__ __launch_bounds__(256) void k_gate(
    const float* __restrict__ x, const float* __restrict__ gw,
    int* __restrict__ topi, float* __restrict__ wts,
    int* __restrict__ pcnt, float* __restrict__ pps, u16* __restrict__ xb)
{
    __shared__ int   cnt[NEXP];
    __shared__ float ps[NEXP];
    const int tid = threadIdx.x;
    if (tid < NEXP) { cnt[tid] = 0; ps[tid] = 0.f; }
    __syncthreads();
    const int wid = tid >> 6, lane = tid & 63;

    const float4* gw4 = (const float4*)gw;
    float4 g0[NEXP], g1[NEXP];
#pragma unroll
    for (int e = 0; e < NEXP; e++) {
        g0[e] = gw4[e * 128 + lane];
        g1[e] = gw4[e * 128 + 64 + lane];
    }

    const int t0 = blockIdx.x * 64 + wid * 16;
    for (int u = 0; u < 16; u++) {
        int t = t0 + u;
        const float4* xr4 = (const float4*)(x + (size_t)t * DDIM);
        float4 v0 = xr4[lane];
        float4 v1 = xr4[64 + lane];
        ushort4 o0 = { f2bf(v0.x), f2bf(v0.y), f2bf(v0.z), f2bf(v0.w) };
        ushort4 o1 = { f2bf(v1.x), f2bf(v1.y), f2bf(v1.z), f2bf(v1.w) };
        ushort4* xbo = (ushort4*)(xb + (size_t)t * DDIM);
        xbo[lane] = o0;
        xbo[64 + lane] = o1;
        float acc[NEXP];
#pragma unroll
        for (int e = 0; e < NEXP; e++) {
            acc[e] = v0.x * g0[e].x + v0.y * g0[e].y + v0.z * g0[e].z + v0.w * g0[e].w
                   + v1.x * g1[e].x + v1.y * g1[e].y + v1.z * g1[e].z + v1.w * g1[e].w;
        }
#pragma unroll
        for (int e = 0; e < NEXP; e++) {
#pragma unroll
            for (int off = 32; off; off >>= 1) acc[e] += __shfl_xor(acc[e], off, 64);
        }
        if (lane == 0) {
            float s[NEXP];
#pragma unroll
            for (int e = 0; e < NEXP; e++) s[e] = 1.f / (1.f + expf(-acc[e]));
            int i1 = 0; float v1s = s[0];
#pragma unroll
            for (int e = 1; e < NEXP; e++) if (s[e] > v1s) { v1s = s[e]; i1 = e; }
            int i2 = -1; float v2s = -1.f;
#pragma unroll
            for (int e = 0; e < NEXP; e++) if (e != i1 && s[e] > v2s) { v2s = s[e]; i2 = e; }
            float inv = 1.f / (v1s + v2s);
            float wa = v1s * inv, wb = v2s * inv;  // ROUTE_SCALE = 1.0
            topi[2 * t] = i1; topi[2 * t + 1] = i2;
            wts[2 * t] = wa;  wts[2 * t + 1] = wb;
            atomicAdd(&cnt[i1], 1); atomicAdd(&cnt[i2], 1);   // LDS atomics
            atomicAdd(&ps[i1], wa); atomicAdd(&ps[i2], wb);
        }
    }
    __syncthreads();
    if (tid < NEXP) {
        pcnt[blockIdx.x * NEXP + tid] = cnt[tid];
        pps[blockIdx.x * NEXP + tid]  = ps[tid];
    }
}

// Reduce per-block partials; 256-padded exclusive prefix; aux loss.
__global__ void k_scan(const int* __restrict__ pcnt, const float* __restrict__ pps,
                       int* __restrict__ off_pad, float* __restrict__ out_loss)
{
    __shared__ int   scnt[8][NEXP];
    __shared__ float sps[8][NEXP];
    int tid = threadIdx.x;
    if (tid < 64) {
        int e = tid & 7, part = tid >> 3;
        int c = 0; float p = 0.f;
        for (int b = part * 32; b < part * 32 + 32; b++) {
            c += pcnt[b * NEXP + e];
            p += pps[b * NEXP + e];
        }
        scnt[part][e] = c; sps[part][e] = p;
    }
    __syncthreads();
    if (tid == 0) {
        int off = 0; float L = 0.f;
        for (int e = 0; e < NEXP; e++) {
            int c = 0; float p = 0.f;
            for (int q = 0; q < 8; q++) { c += scnt[q][e]; p += sps[q][e]; }
            off_pad[e] = off;
            off += (c + 255) & ~255;       // pad segments to 256 (s1 M-tile)
            float f = (float)NEXP * (float)c / (float)(2 * T_TOK);
            L += f * (p / (float)T_TOK);
        }
        off_pad[NEXP] = off;
        out_loss[0] = L;
    }
}

__global__ void k_fillperm(int* __restrict__ perm) {
    int i = blockIdx.x * blockDim.x + threadIdx.x;
    if (i < MPAD) perm[i] = -1;
}

// 256 tokens/block: LDS histogram -> one global atomicAdd per expert per block.
__global__ __launch_bounds__(256) void k_scatter(
    const int* __restrict__ topi, const float* __restrict__ wts,
    const int* __restrict__ off_pad, int* __restrict__ cursors,
    int* __restrict__ perm, float* __restrict__ pw, int* __restrict__ inv)
{
    __shared__ int lcnt[NEXP];
    __shared__ int lbase[NEXP];
    int tid = threadIdx.x;
    if (tid < NEXP) lcnt[tid] = 0;
    __syncthreads();
    int t = blockIdx.x * 256 + tid;
    int e0 = topi[2 * t], e1 = topi[2 * t + 1];
    int p0 = atomicAdd(&lcnt[e0], 1);
    int p1 = atomicAdd(&lcnt[e1], 1);
    __syncthreads();
    if (tid < NEXP) lbase[tid] = atomicAdd(&cursors[tid], lcnt[tid]);
    __syncthreads();
    int s0 = off_pad[e0] + lbase[e0] + p0;
    int s1 = off_pad[e1] + lbase[e1] + p1;
    perm[s0] = t; pw[s0] = wts[2 * t];
    perm[s1] = t; pw[s1] = wts[2 * t + 1];
    inv[2 * t] = s0; inv[2 * t + 1] = s1;
}

// xg[slot] = xb[perm[slot]] (bf16 copy) or 0
__global__ __launch_bounds__(256) void k_gather(const u16* __restrict__ xb,
                                                const int* __restrict__ perm,
                                                u16* __restrict__ xg) {
    int row = blockIdx.x * 2 + (threadIdx.x >> 7);
    int c = (threadIdx.x & 127) * 4;
    int tok = perm[row];
    ushort4 v = {0, 0, 0, 0};
    if (tok >= 0) v = *(const ushort4*)&xb[(size_t)tok * DDIM + c];
    *(ushort4*)&xg[(size_t)row * DDIM + c] = v;
}

// Transpose + bf16 cast with row remap: dst row r' = (c>>7)*rmul + (c&127) + radd.
// plain transpose: rmul=128, radd=0 (r'=c). grid (C/64, R/64, nmat)
__global__ __launch_bounds__(256) void k_transpose(const float* __restrict__ src,
                                                   u16* __restrict__ dst, int R, int C,
                                                   int rmul, int radd, int zrows)
{
    __shared__ u16 t[64][68];
    const float* s = src + (size_t)blockIdx.z * R * C;
    u16* d = dst + (size_t)blockIdx.z * zrows * R;
    int r0 = blockIdx.y * 64, c0 = blockIdx.x * 64;
    int tid = threadIdx.x;
    int lr = tid >> 4, lc = (tid & 15) * 4;
#pragma unroll
    for (int u = 0; u < 4; u++) {
        int r = lr + u * 16;
        float4 v = *(const float4*)&s[(size_t)(r0 + r) * C + c0 + lc];
        t[lc + 0][r] = f2bf(v.x);
        t[lc + 1][r] = f2bf(v.y);
        t[lc + 2][r] = f2bf(v.z);
        t[lc + 3][r] = f2bf(v.w);
    }
    __syncthreads();
    int wr = tid >> 4, wc = (tid & 15) * 4;
#pragma unroll
    for (int u = 0; u < 4; u++) {
        int c = wr + u * 16;
        int gc = c0 + c;
        int rp = (gc >> 7) * rmul + (gc & 127) + radd;
        ushort4 o = { t[c][wc], t[c][wc + 1], t[c][wc + 2], t[c][wc + 3] };
        *(ushort4*)&d[(size_t)rp * R + r0 + wc] = o;
    }
}

// ---------------- s1: 256x256 tile, BK=64, 8 waves, counted-vmcnt phase schedule ----------------
// A: [M][512] bf16. Bt: interleaved w13T [N'][512]: each 256-row group = 128 w1-cols | 128 w3-cols.
// Output: H[m][nt*128 + c] = silu(C1+b1) * (C3+b3), bf16.
template<bool ROUTED, bool BIAS, int NTX>
__global__ __launch_bounds__(512, 2) void k_s1(
    const u16* __restrict__ A, const u16* __restrict__ Bt,
    const float* __restrict__ bias1, const float* __restrict__ bias3,
    u16* __restrict__ H, int ldh, const int* __restrict__ off_pad)
{
    __shared__ __align__(16) unsigned char smem[131072];  // A 2x32KB | B 2x32KB ; epilogue alias f32[256][128]
    const int K = DDIM;        // 512
    const int NT = K / 64;     // 8 K-tiles

    const int nwg = NTX * gridDim.y;
    int id = blockIdx.y * NTX + blockIdx.x;
    id = xcd_swz(id, nwg);
    const int mt = id / NTX, nt = id % NTX;
    const int m0 = mt * 256;
    if (ROUTED && m0 >= off_pad[NEXP]) return;
    const u16* B = Bt;
    if (ROUTED) {
        int e = 0;
        while (off_pad[e + 1] <= m0) e++;
        B += (size_t)e * (2 * IDIM) * DDIM;   // per-expert 2048 rows x 512
    }
    const int n0r = nt * 256;   // B row offset

    const int tid = threadIdx.x;
    const int wid = tid >> 6, lane = tid & 63;
    const int wm = wid >> 2, wn = wid & 3;
    const int fr = lane & 15, hi = lane >> 4;

    // staging: 4 sweeps per operand per K-tile; dest byte = s*8192 + tid*16 (linear);
    // source K-group inverse-swizzled so read-side XOR yields correct data (rule #21).
    int srow[4], sgo[4];
#pragma unroll
    for (int s = 0; s < 4; s++) {
        int r = s * 64 + (tid >> 3);
        srow[s] = r;
        sgo[s] = ((tid & 7) ^ (r & 7)) * 8;   // element offset within 64-K row
    }
    const int ldsw = wid * 1024;   // wave-uniform byte base within sweep

    f32x4 acc[8][4];
#pragma unroll
    for (int i = 0; i < 8; i++)
#pragma unroll
        for (int j = 0; j < 4; j++) acc[i][j] = {0.f, 0.f, 0.f, 0.f};

    // prologue: stage tile 0
#pragma unroll
    for (int s = 0; s < 4; s++)
        gload_lds16(A + (size_t)(m0 + srow[s]) * K + sgo[s], smem + s * 8192 + ldsw);
#pragma unroll
    for (int s = 0; s < 4; s++)
        gload_lds16(B + (size_t)(n0r + srow[s]) * K + sgo[s], smem + 65536 + s * 8192 + ldsw);

    const int ar0 = wm * 128;
    const int br0 = wn * 64;

    for (int t = 0; t < NT; t++) {
        const int cur = (t & 1) << 15;          // 0 / 32768
        const int nxt = cur ^ 32768;
        const int k0n = (t + 1) * 64;
        // ---- phase 0: stage next A, counted wait, barrier, kk=0 compute
        if (t + 1 < NT) {
#pragma unroll
            for (int s = 0; s < 4; s++)
                gload_lds16(A + (size_t)(m0 + srow[s]) * K + k0n + sgo[s],
                            smem + nxt + s * 8192 + ldsw);
            asm volatile("s_waitcnt vmcnt(4)" ::: "memory");   // tile t fully landed; new A in flight
        } else {
            asm volatile("s_waitcnt vmcnt(0)" ::: "memory");   // final tile: drain once
        }
        __builtin_amdgcn_s_barrier();
        __builtin_amdgcn_sched_barrier(0);
        {
            bf16x8 av[8], bv[4];
#pragma unroll
            for (int j = 0; j < 4; j++) {
                int br = br0 + j * 16 + fr;
                bv[j] = *(const bf16x8*)(smem + 65536 + cur + br * 128 + (((hi) ^ (br & 7)) << 4));
            }
#pragma unroll
            for (int i = 0; i < 8; i++) {
                int ar = ar0 + i * 16 + fr;
                av[i] = *(const bf16x8*)(smem + cur + ar * 128 + (((hi) ^ (ar & 7)) << 4));
            }
            __builtin_amdgcn_s_setprio(1);
#pragma unroll
            for (int i = 0; i < 8; i++)
#pragma unroll
                for (int j = 0; j < 4; j++)
                    acc[i][j] = __builtin_amdgcn_mfma_f32_16x16x32_bf16(av[i], bv[j], acc[i][j], 0, 0, 0);
            __builtin_amdgcn_s_setprio(0);
        }
        // ---- phase 1: stage next B, kk=32 compute, trailing barrier
        if (t + 1 < NT) {
#pragma unroll
            for (int s = 0; s < 4; s++)
                gload_lds16(B + (size_t)(n0r + srow[s]) * K + k0n + sgo[s],
                            smem + 65536 + nxt + s * 8192 + ldsw);
        }
        {
            bf16x8 av[8], bv[4];
#pragma unroll
            for (int j = 0; j < 4; j++) {
                int br = br0 + j * 16 + fr;
                bv[j] = *(const bf16x8*)(smem + 65536 + cur + br * 128 + (((4 + hi) ^ (br & 7)) << 4));
            }
#pragma unroll
            for (int i = 0; i < 8; i++) {
                int ar = ar0 + i * 16 + fr;
                av[i] = *(const bf16x8*)(smem + cur + ar * 128 + (((4 + hi) ^ (ar & 7)) << 4));
            }
            __builtin_amdgcn_s_setprio(1);
#pragma unroll
            for (int i = 0; i < 8; i++)
#pragma unroll
                for (int j = 0; j < 4; j++)
                    acc[i][j] = __builtin_amdgcn_mfma_f32_16x16x32_bf16(av[i], bv[j], acc[i][j], 0, 0, 0);
            __builtin_amdgcn_s_setprio(0);
        }
        __builtin_amdgcn_s_barrier();          // protects slot overwrite next iter
        __builtin_amdgcn_sched_barrier(0);
    }

    // ---- epilogue: pair C1 (waves wn<2) with C3 (waves wn>=2) via LDS, SwiGLU, store h
    float* c3ex = (float*)smem;   // [256][128] f32 = 128KB (aliases staging LDS; all reads done)
    if (wn >= 2) {
#pragma unroll
        for (int i = 0; i < 8; i++)
#pragma unroll
            for (int j = 0; j < 4; j++) {
                int colb = (wn - 2) * 64 + j * 16 + fr;
#pragma unroll
                for (int r = 0; r < 4; r++) {
                    int row = wm * 128 + i * 16 + hi * 4 + r;
                    c3ex[row * 128 + colb] = acc[i][j][r];
                }
            }
    }
    __syncthreads();
    if (wn < 2) {
#pragma unroll
        for (int i = 0; i < 8; i++)
#pragma unroll
            for (int j = 0; j < 4; j++) {
                int colb = wn * 64 + j * 16 + fr;
                int gcol = nt * 128 + colb;
                float b1 = BIAS ? bias1[gcol] : 0.f;
                float b3 = BIAS ? bias3[gcol] : 0.f;
#pragma unroll
                for (int r = 0; r < 4; r++) {
                    int row = wm * 128 + i * 16 + hi * 4 + r;
                    float v1 = acc[i][j][r] + b1;
                    float v3 = c3ex[row * 128 + colb] + b3;
                    float hv = (v1 / (1.f + __expf(-v1))) * v3;
                    H[(size_t)(m0 + row) * ldh + gcol] = f2bf(hv);
                }
            }
    }
}

// ---------------- s2: 128x128 tile, BK=32, double-buffered (proven R4 structure) ----------------
template<int K, bool ROUTED>
__global__ __launch_bounds__(256, 2) void k_s2(
    const u16* __restrict__ A, const u16* __restrict__ Bt,
    const float* __restrict__ bias2, float* __restrict__ out,
    u16* __restrict__ ytmp, const int* __restrict__ off_pad)
{
    __shared__ __align__(16) u16 sA[2][128 * 32], sB[2][128 * 32];
    const int nwg = gridDim.x * gridDim.y;
    const int id  = xcd_swz(blockIdx.y * gridDim.x + blockIdx.x, nwg);
    const int m0 = (id / gridDim.x) * 128;
    const int n0 = (id % gridDim.x) * 128;
    if (ROUTED && m0 >= off_pad[NEXP]) return;
    const u16* bt = Bt;
    if (ROUTED) {
        int e = 0;
        while (off_pad[e + 1] <= m0) e++;
        bt += (size_t)e * DDIM * IDIM;
    }
    const int tid = threadIdx.x;
    const int wid = tid >> 6, lane = tid & 63;
    const int srow = wid * 16 + (lane >> 2);
    const int skk  = (lane & 3) * 8;
    const u16* gA = A  + (size_t)(m0 + srow) * K + skk;
    const u16* gB = bt + (size_t)(n0 + srow) * K + skk;
    const int ldst = wid * 512;
    const int fr = lane & 15;
    const int fk = (lane >> 4) * 8;
    const int wrow = (wid >> 1) * 64, wcol = (wid & 1) * 64;

    f32x4 acc[4][4];
#pragma unroll
    for (int i = 0; i < 4; i++)
#pragma unroll
        for (int j = 0; j < 4; j++) acc[i][j] = {0.f, 0.f, 0.f, 0.f};

#pragma unroll
    for (int p = 0; p < 2; p++) {
        gload_lds16(gA + (size_t)p * 64 * K, &sA[0][ldst + p * 2048]);
        gload_lds16(gB + (size_t)p * 64 * K, &sB[0][ldst + p * 2048]);
    }
    __syncthreads();

    int cur = 0;
    for (int k0 = 0; k0 < K; k0 += 32) {
        if (k0 + 32 < K) {
#pragma unroll
            for (int p = 0; p < 2; p++) {
                gload_lds16(gA + (size_t)p * 64 * K + k0 + 32, &sA[cur ^ 1][ldst + p * 2048]);
                gload_lds16(gB + (size_t)p * 64 * K + k0 + 32, &sB[cur ^ 1][ldst + p * 2048]);
            }
        }
        bf16x8 av[4], bv[4];
#pragma unroll
        for (int i = 0; i < 4; i++) {
            av[i] = *(const bf16x8*)(&sA[cur][(wrow + i * 16 + fr) * 32 + fk]);
            bv[i] = *(const bf16x8*)(&sB[cur][(wcol + i * 16 + fr) * 32 + fk]);
        }
#pragma unroll
        for (int i = 0; i < 4; i++)
#pragma unroll
            for (int j = 0; j < 4; j++)
                acc[i][j] = __builtin_amdgcn_mfma_f32_16x16x32_bf16(av[i], bv[j], acc[i][j], 0, 0, 0);
        __syncthreads();
        cur ^= 1;
    }

    const int rr = (lane >> 4) * 4;
#pragma unroll
    for (int i = 0; i < 4; i++) {
#pragma unroll
        for (int r = 0; r < 4; r++) {
            int row = m0 + wrow + i * 16 + rr + r;
#pragma unroll
            for (int j = 0; j < 4; j++) {
                int col = n0 + wcol + j * 16 + fr;
                float v = acc[i][j][r];
                if (ROUTED) {
                    ytmp[(size_t)row * DDIM + col] = f2bf(v);
                } else {
                    out[(size_t)row * DDIM + col] = v + bias2[col];
                }
            }
        }
    }
}

// out[t] += wts[2t]*ytmp[inv[2t]] + wts[2t+1]*ytmp[inv[2t+1]]
__global__ __launch_bounds__(256) void k_combine(
    const u16* __restrict__ ytmp, const int* __restrict__ inv,
    const float* __restrict__ wts, float* __restrict__ out)
{
    int idx = blockIdx.x * 256 + threadIdx.x;
    int t = idx >> 7;
    int c = (idx & 127) * 4;
    int s0 = inv[2 * t], s1 = inv[2 * t + 1];
    float w0 = wts[2 * t], w1 = wts[2 * t + 1];
    ushort4 a = *(const ushort4*)&ytmp[(size_t)s0 * DDIM + c];
    ushort4 b = *(const ushort4*)&ytmp[(size_t)s1 * DDIM + c];
    float4 o = *(float4*)&out[(size_t)t * DDIM + c];
    o.x += w0 * bf2f(a.x) + w1 * bf2f(b.x);
    o.y += w0 * bf2f(a.y) + w1 * bf2f(b.y);
    o.z += w0 * bf2f(a.z) + w1 * bf2f(b.z);
    o.w += w0 * bf2f(a.w) + w1 * bf2f(b.w);
    *(float4*)&out[(size_t)t * DDIM + c] = o;
}

// ---------------- launch ----------------
extern "C" void kernel_launch(void* const* d_in, const int* in_sizes, int n_in,
                              void* d_out, int out_size, void* d_ws, size_t ws_size,
                              hipStream_t stream)
{
    const float* x   = (const float*)d_in[0];
    const float* gw  = (const float*)d_in[1];
    const float* w1  = (const float*)d_in[2];
    const float* w2  = (const float*)d_in[3];
    const float* w3  = (const float*)d_in[4];
    const float* sw1 = (const float*)d_in[5];
    const float* sb1 = (const float*)d_in[6];
    const float* sw2 = (const float*)d_in[7];
    const float* sb2 = (const float*)d_in[8];
    const float* sw3 = (const float*)d_in[9];
    const float* sb3 = (const float*)d_in[10];
    float* out = (float*)d_out;

    char* ws = (char*)d_ws;
    size_t off = 0;
    int*   topi    = (int*)(ws + off);   off += (size_t)2 * T_TOK * 4;
    float* wts     = (float*)(ws + off); off += (size_t)2 * T_TOK * 4;
    int*   perm    = (int*)(ws + off);   off += (size_t)MPAD * 4;
    float* pw      = (float*)(ws + off); off += (size_t)MPAD * 4;
    int*   cursors = (int*)(ws + off);   off += 256;
    int*   off_pad = (int*)(ws + off);   off += 256;
    int*   pcnt    = (int*)(ws + off);   off += (size_t)GBLK * NEXP * 4;
    float* pps     = (float*)(ws + off); off += (size_t)GBLK * NEXP * 4;
    int*   inv     = (int*)(ws + off);   off += (size_t)2 * T_TOK * 4;
    u16*   xb      = (u16*)(ws + off);   off += (size_t)T_TOK * DDIM * 2;
    u16*   xg      = (u16*)(ws + off);   off += (size_t)MPAD * DDIM * 2;
    u16*   w13Ts   = (u16*)(ws + off);   off += (size_t)2 * SHDIM * DDIM * 2;           // [4096][512]
    u16*   w13Tr   = (u16*)(ws + off);   off += (size_t)NEXP * 2 * IDIM * DDIM * 2;     // [8][2048][512]
    u16*   w2T     = (u16*)(ws + off);   off += (size_t)NEXP * DDIM * IDIM * 2;
    u16*   sw2T    = (u16*)(ws + off);   off += (size_t)DDIM * SHDIM * 2;
    u16*   hb      = (u16*)(ws + off);   off += (size_t)MPAD * IDIM * 2;                // reused for shared h too
    u16*   ytmp    = xg;   // xg dead after routed s1 staging reads

    // routing
    k_zero<<<1, 64, 0, stream>>>(cursors);
    k_gate<<<GBLK, 256, 0, stream>>>(x, gw, topi, wts, pcnt, pps, xb);
    k_scan<<<1, 64, 0, stream>>>(pcnt, pps, off_pad, out + (size_t)T_TOK * DDIM);
    k_fillperm<<<MPAD / 256, 256, 0, stream>>>(perm);
    k_scatter<<<T_TOK / 256, 256, 0, stream>>>(topi, wts, off_pad, cursors, perm, pw, inv);
    k_gather<<<MPAD / 2, 256, 0, stream>>>(xb, perm, xg);

    // weights: bf16 transposes. w13T interleaved (128-col groups of w1|w3 per 256 rows).
    k_transpose<<<dim3(SHDIM / 64, DDIM / 64, 1), 256, 0, stream>>>(sw1, w13Ts, DDIM, SHDIM, 256, 0,   2 * SHDIM);
    k_transpose<<<dim3(SHDIM / 64, DDIM / 64, 1), 256, 0, stream>>>(sw3, w13Ts, DDIM, SHDIM, 256, 128, 2 * SHDIM);
    k_transpose<<<dim3(IDIM / 64, DDIM / 64, NEXP), 256, 0, stream>>>(w1, w13Tr, DDIM, IDIM, 256, 0,   2 * IDIM);
    k_transpose<<<dim3(IDIM / 64, DDIM / 64, NEXP), 256, 0, stream>>>(w3, w13Tr, DDIM, IDIM, 256, 128, 2 * IDIM);
    k_transpose<<<dim3(DDIM / 64, IDIM / 64, NEXP), 256, 0, stream>>>(w2, w2T, IDIM, DDIM, 128, 0, DDIM);
    k_transpose<<<dim3(DDIM / 64, SHDIM / 64, 1), 256, 0, stream>>>(sw2, sw2T, SHDIM, DDIM, 128, 0, DDIM);

    // shared expert (h -> hb[16384][2048], then out = h@sw2 + b2)
    k_s1<false, true, 16><<<dim3(16, T_TOK / 256), 512, 0, stream>>>(
        xb, w13Ts, sb1, sb3, hb, SHDIM, nullptr);
    k_s2<SHDIM, false><<<dim3(DDIM / 128, T_TOK / 128), 256, 0, stream>>>(
        hb, sw2T, sb2, out, nullptr, nullptr);
    // routed experts (h -> hb[MPAD][1024], ytmp = h@w2, combine into out)
    k_s1<true, false, 8><<<dim3(8, MPAD / 256), 512, 0, stream>>>(
        xg, w13Tr, nullptr, nullptr, hb, IDIM, off_pad);
    k_s2<IDIM, true><<<dim3(DDIM / 128, MPAD / 128), 256, 0, stream>>>(
        hb, w2T, nullptr, nullptr, ytmp, off_pad);
    k_combine<<<(T_TOK * DDIM / 4) / 256, 256, 0, stream>>>(ytmp, inv, wts, out);
}

// Round 6
// 353.960 us; speedup vs baseline: 1.3120x; 1.3120x over previous
//
#include <hip/hip_runtime.h>
#include <math.h>
#include <stdint.h>

// B=8,S=2048,D=512,I=1024,E=8,K=2,SH=2048 ; T=16384 tokens
#define T_TOK 16384
#define DDIM  512
#define IDIM  1024
#define NEXP  8
#define SHDIM 2048
#define MT_R  264                  // routed M-tiles (2T + 8*127 padded to 128)
#define MPAD  (MT_R * 128)         // 33792 padded routed rows
#define GBLK  256                  // k_gate blocks (64 tokens each)

typedef unsigned short u16;
typedef short bf16x8 __attribute__((ext_vector_type(8)));
typedef float f32x4 __attribute__((ext_vector_type(4)));

__device__ __forceinline__ u16 f2bf(float f) {
    unsigned u = __float_as_uint(f);
    u += 0x7FFF + ((u >> 16) & 1);   // round-to-nearest-even
    return (u16)(u >> 16);
}
__device__ __forceinline__ float bf2f(u16 h) {
    return __uint_as_float((unsigned)h << 16);
}

__device__ __forceinline__ void gload_lds16(const void* g, void* l) {
    __builtin_amdgcn_global_load_lds(
        (const __attribute__((address_space(1))) void*)g,
        (__attribute__((address_space(3))) void*)l, 16, 0, 0);
}

// XCD-chunked bijective block swizzle (T1); nwg % 8 == 0 for all our grids.
__device__ __forceinline__ int xcd_swz(int id, int nwg) {
    return (id & 7) * (nwg >> 3) + (id >> 3);
}

// bank swizzle: k-group permutation within a 64B row, period 8 rows (2-way max)
__device__ __forceinline__ int ksw(int r) { return (r & 3) ^ ((r >> 2) & 3); }

// ---------------- routing ----------------
__global__ void k_zero(int* cursors) {
    int i = threadIdx.x;
    if (i < NEXP) cursors[i] = 0;
}

// 64 tokens/block, 4 waves. No global atomics; fuses x->bf16 (writes xb).
__global__ __launch_bounds__(256) void k_gate(
    const float* __restrict__ x, const float* __restrict__ gw,
    int* __restrict__ topi, float* __restrict__ wts,
    int* __restrict__ pcnt, float* __restrict__ pps, u16* __restrict__ xb)
{
    __shared__ int   cnt[NEXP];
    __shared__ float ps[NEXP];
    const int tid = threadIdx.x;
    if (tid < NEXP) { cnt[tid] = 0; ps[tid] = 0.f; }
    __syncthreads();
    const int wid = tid >> 6, lane = tid & 63;

    const float4* gw4 = (const float4*)gw;
    float4 g0[NEXP], g1[NEXP];
#pragma unroll
    for (int e = 0; e < NEXP; e++) {
        g0[e] = gw4[e * 128 + lane];
        g1[e] = gw4[e * 128 + 64 + lane];
    }

    const int t0 = blockIdx.x * 64 + wid * 16;
    for (int u = 0; u < 16; u++) {
        int t = t0 + u;
        const float4* xr4 = (const float4*)(x + (size_t)t * DDIM);
        float4 v0 = xr4[lane];
        float4 v1 = xr4[64 + lane];
        ushort4 o0 = { f2bf(v0.x), f2bf(v0.y), f2bf(v0.z), f2bf(v0.w) };
        ushort4 o1 = { f2bf(v1.x), f2bf(v1.y), f2bf(v1.z), f2bf(v1.w) };
        ushort4* xbo = (ushort4*)(xb + (size_t)t * DDIM);
        xbo[lane] = o0;
        xbo[64 + lane] = o1;
        float acc[NEXP];
#pragma unroll
        for (int e = 0; e < NEXP; e++) {
            acc[e] = v0.x * g0[e].x + v0.y * g0[e].y + v0.z * g0[e].z + v0.w * g0[e].w
                   + v1.x * g1[e].x + v1.y * g1[e].y + v1.z * g1[e].z + v1.w * g1[e].w;
        }
#pragma unroll
        for (int e = 0; e < NEXP; e++) {
#pragma unroll
            for (int off = 32; off; off >>= 1) acc[e] += __shfl_xor(acc[e], off, 64);
        }
        if (lane == 0) {
            float s[NEXP];
#pragma unroll
            for (int e = 0; e < NEXP; e++) s[e] = 1.f / (1.f + expf(-acc[e]));
            int i1 = 0; float v1s = s[0];
#pragma unroll
            for (int e = 1; e < NEXP; e++) if (s[e] > v1s) { v1s = s[e]; i1 = e; }
            int i2 = -1; float v2s = -1.f;
#pragma unroll
            for (int e = 0; e < NEXP; e++) if (e != i1 && s[e] > v2s) { v2s = s[e]; i2 = e; }
            float inv = 1.f / (v1s + v2s);
            float wa = v1s * inv, wb = v2s * inv;  // ROUTE_SCALE = 1.0
            topi[2 * t] = i1; topi[2 * t + 1] = i2;
            wts[2 * t] = wa;  wts[2 * t + 1] = wb;
            atomicAdd(&cnt[i1], 1); atomicAdd(&cnt[i2], 1);   // LDS atomics
            atomicAdd(&ps[i1], wa); atomicAdd(&ps[i2], wb);
        }
    }
    __syncthreads();
    if (tid < NEXP) {
        pcnt[blockIdx.x * NEXP + tid] = cnt[tid];
        pps[blockIdx.x * NEXP + tid]  = ps[tid];
    }
}

// Reduce per-block partials; 128-padded exclusive prefix; aux loss.
__global__ void k_scan(const int* __restrict__ pcnt, const float* __restrict__ pps,
                       int* __restrict__ off_pad, float* __restrict__ out_loss)
{
    __shared__ int   scnt[8][NEXP];
    __shared__ float sps[8][NEXP];
    int tid = threadIdx.x;
    if (tid < 64) {
        int e = tid & 7, part = tid >> 3;
        int c = 0; float p = 0.f;
        for (int b = part * 32; b < part * 32 + 32; b++) {
            c += pcnt[b * NEXP + e];
            p += pps[b * NEXP + e];
        }
        scnt[part][e] = c; sps[part][e] = p;
    }
    __syncthreads();
    if (tid == 0) {
        int off = 0; float L = 0.f;
        for (int e = 0; e < NEXP; e++) {
            int c = 0; float p = 0.f;
            for (int q = 0; q < 8; q++) { c += scnt[q][e]; p += sps[q][e]; }
            off_pad[e] = off;
            off += (c + 127) & ~127;
            float f = (float)NEXP * (float)c / (float)(2 * T_TOK);
            L += f * (p / (float)T_TOK);
        }
        off_pad[NEXP] = off;
        out_loss[0] = L;
    }
}

// fills perm with -1; also zeroes the 512-elem bf16 zero-page
__global__ void k_fillperm(int* __restrict__ perm, u16* __restrict__ zpad) {
    int i = blockIdx.x * blockDim.x + threadIdx.x;
    if (i < MPAD) perm[i] = -1;
    if (blockIdx.x == 0 && threadIdx.x < 256) ((unsigned*)zpad)[threadIdx.x] = 0u;
}

// 256 tokens/block: LDS histogram -> one global atomicAdd per expert per block.
__global__ __launch_bounds__(256) void k_scatter(
    const int* __restrict__ topi, const float* __restrict__ wts,
    const int* __restrict__ off_pad, int* __restrict__ cursors,
    int* __restrict__ perm, float* __restrict__ pw, int* __restrict__ inv)
{
    __shared__ int lcnt[NEXP];
    __shared__ int lbase[NEXP];
    int tid = threadIdx.x;
    if (tid < NEXP) lcnt[tid] = 0;
    __syncthreads();
    int t = blockIdx.x * 256 + tid;
    int e0 = topi[2 * t], e1 = topi[2 * t + 1];
    int p0 = atomicAdd(&lcnt[e0], 1);
    int p1 = atomicAdd(&lcnt[e1], 1);
    __syncthreads();
    if (tid < NEXP) lbase[tid] = atomicAdd(&cursors[tid], lcnt[tid]);
    __syncthreads();
    int s0 = off_pad[e0] + lbase[e0] + p0;
    int s1 = off_pad[e1] + lbase[e1] + p1;
    perm[s0] = t; pw[s0] = wts[2 * t];
    perm[s1] = t; pw[s1] = wts[2 * t + 1];
    inv[2 * t] = s0; inv[2 * t + 1] = s1;
}

// dst[z][c][r] = bf16(src[z][r][c]) ; grid (C/64, R/64, nmat)
__global__ __launch_bounds__(256) void k_transpose(const float* __restrict__ src,
                                                   u16* __restrict__ dst, int R, int C)
{
    __shared__ u16 t[64][68];
    const float* s = src + (size_t)blockIdx.z * R * C;
    u16* d = dst + (size_t)blockIdx.z * R * C;
    int r0 = blockIdx.y * 64, c0 = blockIdx.x * 64;
    int tid = threadIdx.x;
    int lr = tid >> 4, lc = (tid & 15) * 4;
#pragma unroll
    for (int u = 0; u < 4; u++) {
        int r = lr + u * 16;
        float4 v = *(const float4*)&s[(size_t)(r0 + r) * C + c0 + lc];
        t[lc + 0][r] = f2bf(v.x);
        t[lc + 1][r] = f2bf(v.y);
        t[lc + 2][r] = f2bf(v.z);
        t[lc + 3][r] = f2bf(v.w);
    }
    __syncthreads();
    int wr = tid >> 4, wc = (tid & 15) * 4;
#pragma unroll
    for (int u = 0; u < 4; u++) {
        int c = wr + u * 16;
        ushort4 o = { t[c][wc], t[c][wc + 1], t[c][wc + 2], t[c][wc + 3] };
        *(ushort4*)&d[(size_t)(c0 + c) * R + r0 + wc] = o;
    }
}

// ---------------- s1: 128x128 tile, BK=32, TRIPLE-buffered, counted vmcnt ----------------
// Dual GEMM: H = bf16( silu(A@B1 [+b1]) * (A@B3 [+b3]) ).  A rows gathered via perm if ROUTED.
template<bool ROUTED, bool BIAS>
__global__ __launch_bounds__(256, 2) void k_s1(
    const u16* __restrict__ Axb, const u16* __restrict__ B1t, const u16* __restrict__ B3t,
    const float* __restrict__ bias1, const float* __restrict__ bias3,
    u16* __restrict__ H, int ldh, const int* __restrict__ off_pad,
    const int* __restrict__ perm, const u16* __restrict__ zpad)
{
    __shared__ __align__(16) unsigned char smem[3 * 24576];   // 72KB: 3 bufs x (A|B1|B3 8KB each)
    const int nwg = gridDim.x * gridDim.y;
    const int id  = xcd_swz(blockIdx.y * gridDim.x + blockIdx.x, nwg);
    const int m0 = (id / gridDim.x) * 128;
    const int n0 = (id % gridDim.x) * 128;
    if (ROUTED && m0 >= off_pad[NEXP]) return;
    const u16* b1 = B1t; const u16* b3 = B3t;
    if (ROUTED) {
        int e = 0;
        while (off_pad[e + 1] <= m0) e++;
        b1 += (size_t)e * IDIM * DDIM;
        b3 += (size_t)e * IDIM * DDIM;
    }
    const int tid = threadIdx.x;
    const int wid = tid >> 6, lane = tid & 63;
    const int fr = lane & 15, hi = lane >> 4;
    const int wrow = (wid >> 1) * 64, wcol = (wid & 1) * 64;

    // staging precompute: 2 sweeps per 128x32 operand; linear LDS dest, swizzled source
    const u16* ap[2]; const u16* b1p[2]; const u16* b3p[2];
    int dst_[2];
#pragma unroll
    for (int s = 0; s < 2; s++) {
        int r = s * 64 + (tid >> 2);
        int goff = ((tid & 3) ^ ksw(r)) * 8;
        dst_[s] = s * 4096 + tid * 16;
        if (ROUTED) {
            int tok = perm[m0 + r];
            ap[s] = (tok >= 0 ? Axb + (size_t)tok * DDIM : zpad) + goff;
        } else {
            ap[s] = Axb + (size_t)(m0 + r) * DDIM + goff;
        }
        b1p[s] = b1 + (size_t)(n0 + r) * DDIM + goff;
        b3p[s] = b3 + (size_t)(n0 + r) * DDIM + goff;
    }
    // fragment LDS byte offsets (swizzled read side)
    int aoff[4], boff[4];
#pragma unroll
    for (int i = 0; i < 4; i++) {
        int ar = wrow + i * 16 + fr;
        aoff[i] = ar * 64 + ((hi ^ ksw(ar)) << 4);
        int br = wcol + i * 16 + fr;
        boff[i] = br * 64 + ((hi ^ ksw(br)) << 4);
    }

    f32x4 acc1[4][4], acc3[4][4];
#pragma unroll
    for (int i = 0; i < 4; i++)
#pragma unroll
        for (int j = 0; j < 4; j++) { acc1[i][j] = {0.f, 0.f, 0.f, 0.f}; acc3[i][j] = {0.f, 0.f, 0.f, 0.f}; }

    const int NT = DDIM / 32;   // 16
    // prologue: stage tiles 0,1 into bufs 0,1  (12 loads/thread)
#pragma unroll
    for (int t = 0; t < 2; t++) {
        unsigned char* bb = smem + t * 24576;
#pragma unroll
        for (int s = 0; s < 2; s++) {
            gload_lds16(ap[s]  + t * 32, bb + dst_[s]);
            gload_lds16(b1p[s] + t * 32, bb + 8192  + dst_[s]);
            gload_lds16(b3p[s] + t * 32, bb + 16384 + dst_[s]);
        }
    }

    int bufc = 0;
    for (int t = 0; t < NT; t++) {
        int bufn = bufc + 2; if (bufn >= 3) bufn -= 3;
        if (t + 2 < NT) {                     // stage tile t+2 (6 loads), keep 12 in flight
            unsigned char* bb = smem + bufn * 24576;
            int k2 = (t + 2) * 32;
#pragma unroll
            for (int s = 0; s < 2; s++) {
                gload_lds16(ap[s]  + k2, bb + dst_[s]);
                gload_lds16(b1p[s] + k2, bb + 8192  + dst_[s]);
                gload_lds16(b3p[s] + k2, bb + 16384 + dst_[s]);
            }
            asm volatile("s_waitcnt vmcnt(12)" ::: "memory");   // tile t landed (issued 2 steps ago)
        } else if (t + 2 == NT) {
            asm volatile("s_waitcnt vmcnt(6)" ::: "memory");
        } else {
            asm volatile("s_waitcnt vmcnt(0)" ::: "memory");
        }
        __builtin_amdgcn_s_barrier();
        __builtin_amdgcn_sched_barrier(0);
        const unsigned char* cb = smem + bufc * 24576;
        bf16x8 av[4], b1v[4], b3v[4];
#pragma unroll
        for (int i = 0; i < 4; i++) {
            av[i]  = *(const bf16x8*)(cb + aoff[i]);
            b1v[i] = *(const bf16x8*)(cb + 8192  + boff[i]);
            b3v[i] = *(const bf16x8*)(cb + 16384 + boff[i]);
        }
        __builtin_amdgcn_s_setprio(1);
#pragma unroll
        for (int i = 0; i < 4; i++)
#pragma unroll
            for (int j = 0; j < 4; j++) {
                acc1[i][j] = __builtin_amdgcn_mfma_f32_16x16x32_bf16(av[i], b1v[j], acc1[i][j], 0, 0, 0);
                acc3[i][j] = __builtin_amdgcn_mfma_f32_16x16x32_bf16(av[i], b3v[j], acc3[i][j], 0, 0, 0);
            }
        __builtin_amdgcn_s_setprio(0);
        __builtin_amdgcn_sched_barrier(0);
        __builtin_amdgcn_s_barrier();        // reads of bufc retired before next-iter overwrite
        bufc++; if (bufc >= 3) bufc -= 3;
    }

    const int rr = hi * 4;
#pragma unroll
    for (int i = 0; i < 4; i++) {
#pragma unroll
        for (int j = 0; j < 4; j++) {
            int col = n0 + wcol + j * 16 + fr;
            float bb1 = BIAS ? bias1[col] : 0.f;
            float bb3 = BIAS ? bias3[col] : 0.f;
#pragma unroll
            for (int r = 0; r < 4; r++) {
                int row = m0 + wrow + i * 16 + rr + r;
                float v1 = acc1[i][j][r] + bb1;
                float v3 = acc3[i][j][r] + bb3;
                float hv = (v1 / (1.f + __expf(-v1))) * v3;
                H[(size_t)row * ldh + col] = f2bf(hv);
            }
        }
    }
}

// ---------------- s2: 128x128 tile, BK=32, TRIPLE-buffered, counted vmcnt ----------------
template<int K, bool ROUTED>
__global__ __launch_bounds__(256, 3) void k_s2(
    const u16* __restrict__ A, const u16* __restrict__ Bt,
    const float* __restrict__ bias2, float* __restrict__ out,
    u16* __restrict__ ytmp, const int* __restrict__ off_pad)
{
    __shared__ __align__(16) unsigned char smem[3 * 16384];   // 48KB: 3 bufs x (A|B 8KB each)
    const int nwg = gridDim.x * gridDim.y;
    const int id  = xcd_swz(blockIdx.y * gridDim.x + blockIdx.x, nwg);
    const int m0 = (id / gridDim.x) * 128;
    const int n0 = (id % gridDim.x) * 128;
    if (ROUTED && m0 >= off_pad[NEXP]) return;
    const u16* bt = Bt;
    if (ROUTED) {
        int e = 0;
        while (off_pad[e + 1] <= m0) e++;
        bt += (size_t)e * DDIM * IDIM;
    }
    const int tid = threadIdx.x;
    const int wid = tid >> 6, lane = tid & 63;
    const int fr = lane & 15, hi = lane >> 4;
    const int wrow = (wid >> 1) * 64, wcol = (wid & 1) * 64;

    const u16* ap[2]; const u16* bp[2];
    int dst_[2];
#pragma unroll
    for (int s = 0; s < 2; s++) {
        int r = s * 64 + (tid >> 2);
        int goff = ((tid & 3) ^ ksw(r)) * 8;
        dst_[s] = s * 4096 + tid * 16;
        ap[s] = A  + (size_t)(m0 + r) * K + goff;
        bp[s] = bt + (size_t)(n0 + r) * K + goff;
    }
    int aoff[4], boff[4];
#pragma unroll
    for (int i = 0; i < 4; i++) {
        int ar = wrow + i * 16 + fr;
        aoff[i] = ar * 64 + ((hi ^ ksw(ar)) << 4);
        int br = wcol + i * 16 + fr;
        boff[i] = br * 64 + ((hi ^ ksw(br)) << 4);
    }

    f32x4 acc[4][4];
#pragma unroll
    for (int i = 0; i < 4; i++)
#pragma unroll
        for (int j = 0; j < 4; j++) acc[i][j] = {0.f, 0.f, 0.f, 0.f};

    const int NT = K / 32;
#pragma unroll
    for (int t = 0; t < 2; t++) {
        unsigned char* bb = smem + t * 16384;
#pragma unroll
        for (int s = 0; s < 2; s++) {
            gload_lds16(ap[s] + t * 32, bb + dst_[s]);
            gload_lds16(bp[s] + t * 32, bb + 8192 + dst_[s]);
        }
    }

    int bufc = 0;
    for (int t = 0; t < NT; t++) {
        int bufn = bufc + 2; if (bufn >= 3) bufn -= 3;
        if (t + 2 < NT) {
            unsigned char* bb = smem + bufn * 16384;
            int k2 = (t + 2) * 32;
#pragma unroll
            for (int s = 0; s < 2; s++) {
                gload_lds16(ap[s] + k2, bb + dst_[s]);
                gload_lds16(bp[s] + k2, bb + 8192 + dst_[s]);
            }
            asm volatile("s_waitcnt vmcnt(8)" ::: "memory");
        } else if (t + 2 == NT) {
            asm volatile("s_waitcnt vmcnt(4)" ::: "memory");
        } else {
            asm volatile("s_waitcnt vmcnt(0)" ::: "memory");
        }
        __builtin_amdgcn_s_barrier();
        __builtin_amdgcn_sched_barrier(0);
        const unsigned char* cb = smem + bufc * 16384;
        bf16x8 av[4], bv[4];
#pragma unroll
        for (int i = 0; i < 4; i++) {
            av[i] = *(const bf16x8*)(cb + aoff[i]);
            bv[i] = *(const bf16x8*)(cb + 8192 + boff[i]);
        }
        __builtin_amdgcn_s_setprio(1);
#pragma unroll
        for (int i = 0; i < 4; i++)
#pragma unroll
            for (int j = 0; j < 4; j++)
                acc[i][j] = __builtin_amdgcn_mfma_f32_16x16x32_bf16(av[i], bv[j], acc[i][j], 0, 0, 0);
        __builtin_amdgcn_s_setprio(0);
        __builtin_amdgcn_sched_barrier(0);
        __builtin_amdgcn_s_barrier();
        bufc++; if (bufc >= 3) bufc -= 3;
    }

    const int rr = hi * 4;
#pragma unroll
    for (int i = 0; i < 4; i++) {
#pragma unroll
        for (int r = 0; r < 4; r++) {
            int row = m0 + wrow + i * 16 + rr + r;
#pragma unroll
            for (int j = 0; j < 4; j++) {
                int col = n0 + wcol + j * 16 + fr;
                float v = acc[i][j][r];
                if (ROUTED) {
                    ytmp[(size_t)row * DDIM + col] = f2bf(v);
                } else {
                    out[(size_t)row * DDIM + col] = v + bias2[col];
                }
            }
        }
    }
}

// out[t] += wts[2t]*ytmp[inv[2t]] + wts[2t+1]*ytmp[inv[2t+1]]
__global__ __launch_bounds__(256) void k_combine(
    const u16* __restrict__ ytmp, const int* __restrict__ inv,
    const float* __restrict__ wts, float* __restrict__ out)
{
    int idx = blockIdx.x * 256 + threadIdx.x;
    int t = idx >> 7;
    int c = (idx & 127) * 4;
    int s0 = inv[2 * t], s1 = inv[2 * t + 1];
    float w0 = wts[2 * t], w1 = wts[2 * t + 1];
    ushort4 a = *(const ushort4*)&ytmp[(size_t)s0 * DDIM + c];
    ushort4 b = *(const ushort4*)&ytmp[(size_t)s1 * DDIM + c];
    float4 o = *(float4*)&out[(size_t)t * DDIM + c];
    o.x += w0 * bf2f(a.x) + w1 * bf2f(b.x);
    o.y += w0 * bf2f(a.y) + w1 * bf2f(b.y);
    o.z += w0 * bf2f(a.z) + w1 * bf2f(b.z);
    o.w += w0 * bf2f(a.w) + w1 * bf2f(b.w);
    *(float4*)&out[(size_t)t * DDIM + c] = o;
}

// ---------------- launch ----------------
extern "C" void kernel_launch(void* const* d_in, const int* in_sizes, int n_in,
                              void* d_out, int out_size, void* d_ws, size_t ws_size,
                              hipStream_t stream)
{
    const float* x   = (const float*)d_in[0];
    const float* gw  = (const float*)d_in[1];
    const float* w1  = (const float*)d_in[2];
    const float* w2  = (const float*)d_in[3];
    const float* w3  = (const float*)d_in[4];
    const float* sw1 = (const float*)d_in[5];
    const float* sb1 = (const float*)d_in[6];
    const float* sw2 = (const float*)d_in[7];
    const float* sb2 = (const float*)d_in[8];
    const float* sw3 = (const float*)d_in[9];
    const float* sb3 = (const float*)d_in[10];
    float* out = (float*)d_out;

    char* ws = (char*)d_ws;
    size_t off = 0;
    int*   topi    = (int*)(ws + off);   off += (size_t)2 * T_TOK * 4;
    float* wts     = (float*)(ws + off); off += (size_t)2 * T_TOK * 4;
    int*   perm    = (int*)(ws + off);   off += (size_t)MPAD * 4;
    float* pw      = (float*)(ws + off); off += (size_t)MPAD * 4;
    int*   cursors = (int*)(ws + off);   off += 256;
    int*   off_pad = (int*)(ws + off);   off += 256;
    int*   pcnt    = (int*)(ws + off);   off += (size_t)GBLK * NEXP * 4;
    float* pps     = (float*)(ws + off); off += (size_t)GBLK * NEXP * 4;
    int*   inv     = (int*)(ws + off);   off += (size_t)2 * T_TOK * 4;
    u16*   zpad    = (u16*)(ws + off);   off += 1024;
    u16*   xb      = (u16*)(ws + off);   off += (size_t)T_TOK * DDIM * 2;
    u16*   ytmp    = (u16*)(ws + off);   off += (size_t)MPAD * DDIM * 2;
    u16*   w1T     = (u16*)(ws + off);   off += (size_t)NEXP * IDIM * DDIM * 2;
    u16*   w3T     = (u16*)(ws + off);   off += (size_t)NEXP * IDIM * DDIM * 2;
    u16*   w2T     = (u16*)(ws + off);   off += (size_t)NEXP * DDIM * IDIM * 2;
    u16*   sw1T    = (u16*)(ws + off);   off += (size_t)SHDIM * DDIM * 2;
    u16*   sw3T    = (u16*)(ws + off);   off += (size_t)SHDIM * DDIM * 2;
    u16*   sw2T    = (u16*)(ws + off);   off += (size_t)DDIM * SHDIM * 2;
    u16*   hb      = (u16*)(ws + off);   off += (size_t)MPAD * IDIM * 2;   // shared h (16384x2048) fits too

    // routing
    k_zero<<<1, 64, 0, stream>>>(cursors);
    k_gate<<<GBLK, 256, 0, stream>>>(x, gw, topi, wts, pcnt, pps, xb);
    k_scan<<<1, 64, 0, stream>>>(pcnt, pps, off_pad, out + (size_t)T_TOK * DDIM);
    k_fillperm<<<MPAD / 256, 256, 0, stream>>>(perm, zpad);
    k_scatter<<<T_TOK / 256, 256, 0, stream>>>(topi, wts, off_pad, cursors, perm, pw, inv);

    // weight transposes (fp32 -> bf16 [N][K])
    k_transpose<<<dim3(IDIM / 64, DDIM / 64, NEXP), 256, 0, stream>>>(w1, w1T, DDIM, IDIM);
    k_transpose<<<dim3(IDIM / 64, DDIM / 64, NEXP), 256, 0, stream>>>(w3, w3T, DDIM, IDIM);
    k_transpose<<<dim3(DDIM / 64, IDIM / 64, NEXP), 256, 0, stream>>>(w2, w2T, IDIM, DDIM);
    k_transpose<<<dim3(SHDIM / 64, DDIM / 64, 1), 256, 0, stream>>>(sw1, sw1T, DDIM, SHDIM);
    k_transpose<<<dim3(SHDIM / 64, DDIM / 64, 1), 256, 0, stream>>>(sw3, sw3T, DDIM, SHDIM);
    k_transpose<<<dim3(DDIM / 64, SHDIM / 64, 1), 256, 0, stream>>>(sw2, sw2T, SHDIM, DDIM);

    // shared expert (out = z)
    k_s1<false, true><<<dim3(SHDIM / 128, T_TOK / 128), 256, 0, stream>>>(
        xb, sw1T, sw3T, sb1, sb3, hb, SHDIM, nullptr, nullptr, nullptr);
    k_s2<SHDIM, false><<<dim3(DDIM / 128, T_TOK / 128), 256, 0, stream>>>(
        hb, sw2T, sb2, out, nullptr, nullptr);
    // routed experts (gather fused into s1 staging) -> ytmp, combine into out
    k_s1<true, false><<<dim3(IDIM / 128, MT_R), 256, 0, stream>>>(
        xb, w1T, w3T, nullptr, nullptr, hb, IDIM, off_pad, perm, zpad);
    k_s2<IDIM, true><<<dim3(DDIM / 128, MT_R), 256, 0, stream>>>(
        hb, w2T, nullptr, nullptr, ytmp, off_pad);
    k_combine<<<(T_TOK * DDIM / 4) / 256, 256, 0, stream>>>(ytmp, inv, wts, out);
}